// Round 1
// baseline (653.617 us; speedup 1.0000x reference)
//
#include <hip/hip_runtime.h>
#include <stdint.h>

typedef _Float16 f16x8 __attribute__((ext_vector_type(8)));
typedef _Float16 f16x4 __attribute__((ext_vector_type(4)));
typedef float    f32x4 __attribute__((ext_vector_type(4)));

#define NFIELD 64
#define DIM    128
#define BTOT   8192

// ---------------- prep: fp16 conversions + W transpose into workspace ----------------
// Wt[i][d][j] = W[i][j][d] (fp16), Kh = fp16(K_w), Qh = fp16(Q_w)
__global__ void prep_kernel(const float* __restrict__ W,
                            const float* __restrict__ Kw,
                            const float* __restrict__ Qw,
                            _Float16* __restrict__ Wt,
                            _Float16* __restrict__ Kh,
                            _Float16* __restrict__ Qh) {
  const int blk = blockIdx.x, t = threadIdx.x;
  if (blk < NFIELD) {
    const float* Wi = W + (size_t)blk * NFIELD * DIM;
    _Float16* Wo = Wt + (size_t)blk * DIM * NFIELD;
    for (int idx = t; idx < DIM * NFIELD; idx += 256) {
      int d = idx >> 6, j = idx & 63;
      Wo[idx] = (_Float16)Wi[j * DIM + d];
    }
  } else if (blk == NFIELD) {
    for (int idx = t; idx < DIM * DIM; idx += 256) Kh[idx] = (_Float16)Kw[idx];
  } else {
    for (int idx = t; idx < DIM * DIM; idx += 256) Qh[idx] = (_Float16)Qw[idx];
  }
}

// ---------------- kernel A: S[b] = F_b @ (F_b @ Kw^T)^T, stored fp16 ----------------
// one block per batch; 4 waves. MFMA 16x16x32 f16.
// A/B frag: row = lane&15, k = quad*8 + j (K-contiguous). C/D: col = lane&15, row = quad*4 + reg.
__global__ __launch_bounds__(256, 3)
void s_kernel(const float* __restrict__ F,
              const _Float16* __restrict__ Kh,
              _Float16* __restrict__ Sg, int c0) {
  __shared__ _Float16 sF[64 * 136];   // F_b fp16, row stride 136 halves (272B, 16-aligned)
  __shared__ float    sKf[64 * 132];  // Kf fp32, row stride 132 floats (528B, 16-aligned)
  const int t = threadIdx.x;
  const int lane = t & 63, wave = t >> 6;
  const int l15 = lane & 15, quad = lane >> 4;
  const int b = c0 + blockIdx.x;
  const float* Fb = F + (size_t)b * (NFIELD * DIM);

  // stage F (fp32 global, coalesced float4) -> sF fp16
  for (int idx = t; idx < 2048; idx += 256) {
    float4 v = ((const float4*)Fb)[idx];
    int row = idx >> 5, c4 = idx & 31;
    f16x4 h;
    h[0] = (_Float16)v.x; h[1] = (_Float16)v.y; h[2] = (_Float16)v.z; h[3] = (_Float16)v.w;
    *(f16x4*)&sF[row * 136 + c4 * 4] = h;
  }
  __syncthreads();

  // Kf[j,e] = sum_d F[j,d] * Kw[e,d]; wave w owns rows j in [16w,16w+16)
  f16x8 afK[4];
#pragma unroll
  for (int kt = 0; kt < 4; ++kt)
    afK[kt] = *(const f16x8*)&sF[(wave * 16 + l15) * 136 + kt * 32 + quad * 8];
#pragma unroll
  for (int et = 0; et < 8; ++et) {
    const _Float16* kp = Kh + (et * 16 + l15) * DIM + quad * 8;
    f32x4 acc = {0.f, 0.f, 0.f, 0.f};
#pragma unroll
    for (int kt = 0; kt < 4; ++kt) {
      f16x8 bf = *(const f16x8*)(kp + kt * 32);
      acc = __builtin_amdgcn_mfma_f32_16x16x32_f16(afK[kt], bf, acc, 0, 0, 0);
    }
    float* op = &sKf[(wave * 16 + quad * 4) * 132 + et * 16 + l15];
    op[0] = acc[0]; op[132] = acc[1]; op[264] = acc[2]; op[396] = acc[3];
  }
  __syncthreads();

  // S[i,j] = sum_e F[i,e] * Kf[j,e]; wave w owns columns j in [16w,16w+16)
  f32x4 accS[4];
#pragma unroll
  for (int it = 0; it < 4; ++it) accS[it] = (f32x4){0.f, 0.f, 0.f, 0.f};
#pragma unroll
  for (int kt = 0; kt < 4; ++kt) {
    const float* bp = &sKf[(wave * 16 + l15) * 132 + kt * 32 + quad * 8];
    float4 b0 = *(const float4*)bp;
    float4 b1 = *(const float4*)(bp + 4);
    f16x8 bf;
    bf[0] = (_Float16)b0.x; bf[1] = (_Float16)b0.y; bf[2] = (_Float16)b0.z; bf[3] = (_Float16)b0.w;
    bf[4] = (_Float16)b1.x; bf[5] = (_Float16)b1.y; bf[6] = (_Float16)b1.z; bf[7] = (_Float16)b1.w;
#pragma unroll
    for (int it = 0; it < 4; ++it) {
      f16x8 af = *(const f16x8*)&sF[(it * 16 + l15) * 136 + kt * 32 + quad * 8];
      accS[it] = __builtin_amdgcn_mfma_f32_16x16x32_f16(af, bf, accS[it], 0, 0, 0);
    }
  }
  _Float16* Sb = Sg + (size_t)blockIdx.x * (NFIELD * NFIELD);
#pragma unroll
  for (int it = 0; it < 4; ++it)
#pragma unroll
    for (int r = 0; r < 4; ++r)
      Sb[(it * 16 + quad * 4 + r) * 64 + wave * 16 + l15] = (_Float16)accS[it][r];
}

// ---------------- kernel B: out[b,i,:] = S[b,i,:]@W[i] + F[b,i,:]@Qw^T ----------------
// grid (b-chunks of 128, i in 0..63). Augmented GEMM: [128 x 192] @ [192 x 128].
// A row b: k<64 -> S[b,i,k] ; k>=64 -> F[b,i,k-64]. B row d (LDS): [Wt[i][d][:64] | Qh[d][:128]].
__global__ __launch_bounds__(256, 3)
void out_kernel(const float* __restrict__ F,
                const _Float16* __restrict__ Sg,
                const _Float16* __restrict__ Wt,
                const _Float16* __restrict__ Qh,
                float* __restrict__ Out, int c0) {
  __shared__ _Float16 sBt[128 * 200];  // row stride 200 halves (400B, 16-aligned)
  const int i = blockIdx.y;
  const int t = threadIdx.x;
  const int lane = t & 63, wave = t >> 6;
  const int l15 = lane & 15, quad = lane >> 4;

  const f16x8* wp = (const f16x8*)(Wt + (size_t)i * DIM * NFIELD);
  for (int idx = t; idx < 1024; idx += 256) {      // 128*64 halves / 8
    int d = idx >> 3, jw = idx & 7;
    *(f16x8*)&sBt[d * 200 + jw * 8] = wp[idx];
  }
  const f16x8* qp = (const f16x8*)Qh;
  for (int idx = t; idx < 2048; idx += 256) {      // 128*128 halves / 8
    int d = idx >> 4, ew = idx & 15;
    *(f16x8*)&sBt[d * 200 + 64 + ew * 8] = qp[idx];
  }
  __syncthreads();

  f32x4 acc[2][8];
#pragma unroll
  for (int mi = 0; mi < 2; ++mi)
#pragma unroll
    for (int nt = 0; nt < 8; ++nt) acc[mi][nt] = (f32x4){0.f, 0.f, 0.f, 0.f};

  const int bl0 = blockIdx.x * 128;
#pragma unroll
  for (int kt = 0; kt < 6; ++kt) {
    f16x8 af[2];
#pragma unroll
    for (int mi = 0; mi < 2; ++mi) {
      const int bl = bl0 + (wave * 2 + mi) * 16 + l15;
      if (kt < 2) {
        const int j0 = kt * 32 + quad * 8;
        af[mi] = *(const f16x8*)(Sg + (size_t)bl * 4096 + i * 64 + j0);
      } else {
        const int e0 = (kt - 2) * 32 + quad * 8;
        const float* fp = F + ((size_t)(c0 + bl) * NFIELD + i) * DIM + e0;
        float4 f0 = *(const float4*)fp;
        float4 f1 = *(const float4*)(fp + 4);
        f16x8 a;
        a[0] = (_Float16)f0.x; a[1] = (_Float16)f0.y; a[2] = (_Float16)f0.z; a[3] = (_Float16)f0.w;
        a[4] = (_Float16)f1.x; a[5] = (_Float16)f1.y; a[6] = (_Float16)f1.z; a[7] = (_Float16)f1.w;
        af[mi] = a;
      }
    }
#pragma unroll
    for (int nt = 0; nt < 8; ++nt) {
      f16x8 bf = *(const f16x8*)&sBt[(nt * 16 + l15) * 200 + kt * 32 + quad * 8];
      acc[0][nt] = __builtin_amdgcn_mfma_f32_16x16x32_f16(af[0], bf, acc[0][nt], 0, 0, 0);
      acc[1][nt] = __builtin_amdgcn_mfma_f32_16x16x32_f16(af[1], bf, acc[1][nt], 0, 0, 0);
    }
  }

#pragma unroll
  for (int mi = 0; mi < 2; ++mi) {
    const int blr = bl0 + (wave * 2 + mi) * 16 + quad * 4;
#pragma unroll
    for (int nt = 0; nt < 8; ++nt) {
      const int d = nt * 16 + l15;
#pragma unroll
      for (int r = 0; r < 4; ++r) {
        const size_t gb = (size_t)(c0 + blr + r);
        Out[(gb * NFIELD + i) * DIM + d] = acc[mi][nt][r];
      }
    }
  }
}

extern "C" void kernel_launch(void* const* d_in, const int* in_sizes, int n_in,
                              void* d_out, int out_size, void* d_ws, size_t ws_size,
                              hipStream_t stream) {
  const float* F  = (const float*)d_in[0];
  const float* W  = (const float*)d_in[1];
  const float* Kw = (const float*)d_in[2];
  const float* Qw = (const float*)d_in[3];
  float* Out = (float*)d_out;

  // workspace layout: Wt (1 MB) | Kh (32 KB) | Qh (32 KB) | S (CB*4096 fp16)
  _Float16* Wt = (_Float16*)d_ws;
  _Float16* Kh = Wt + (size_t)NFIELD * DIM * NFIELD;
  _Float16* Qh = Kh + DIM * DIM;
  _Float16* Sg = Qh + DIM * DIM;
  const size_t fixed_bytes = ((size_t)NFIELD * DIM * NFIELD + 2 * DIM * DIM) * sizeof(_Float16);
  size_t avail = (ws_size > fixed_bytes) ? (ws_size - fixed_bytes) : 0;
  int CB = BTOT;  // batches per chunk; shrink if workspace is small (deterministic per session)
  while (CB > 128 && (size_t)CB * NFIELD * NFIELD * sizeof(_Float16) > avail) CB >>= 1;

  prep_kernel<<<dim3(NFIELD + 2), 256, 0, stream>>>(W, Kw, Qw, Wt, Kh, Qh);
  for (int c0 = 0; c0 < BTOT; c0 += CB) {
    s_kernel<<<dim3(CB), 256, 0, stream>>>(F, Kh, Sg, c0);
    out_kernel<<<dim3(CB / 128, NFIELD), 256, 0, stream>>>(F, Sg, Wt, Qh, Out, c0);
  }
}